// Round 4
// baseline (129.218 us; speedup 1.0000x reference)
//
#include <hip/hip_runtime.h>

#define CIN   256
#define COUT  256
#define HH    64
#define WW    64
#define KD    2304         // CIN * 9
#define NPIX  16384        // B * HO * WO
#define SPLIT 16
#define CPS   (CIN / SPLIT)

typedef __attribute__((ext_vector_type(8))) short  short8v;
typedef __attribute__((ext_vector_type(4))) float  float4v;
typedef __attribute__((ext_vector_type(4))) unsigned short ushort4v;
typedef unsigned int u32;
typedef unsigned short u16;

__device__ __forceinline__ u16 f2bf(float f) {
  union { float f; unsigned u; } v; v.f = f;
  unsigned r = v.u + 0x7FFFu + ((v.u >> 16) & 1u);
  return (u16)(r >> 16);
}
__device__ __forceinline__ float bf2f(u16 h) {
  union { unsigned u; float f; } v; v.u = ((unsigned)h) << 16;
  return v.f;
}

__device__ __forceinline__ void gload_lds16(const void* g, void* l) {
  __builtin_amdgcn_global_load_lds((const __attribute__((address_space(1))) u32*)g,
                                   (__attribute__((address_space(3))) u32*)l, 16, 0, 0);
}

// ---------------- Kernel 1a: offset/mask partials, channel-split ----------------
__global__ __launch_bounds__(256) void offmask_part_kernel(
    const float* __restrict__ x,
    const float* __restrict__ off_dw, const float* __restrict__ off_pw,
    const float* __restrict__ mask_dw, const float* __restrict__ mask_pw,
    float* __restrict__ part)
{
  int m = blockIdx.x * 256 + threadIdx.x;   // pixel id: b*4096 + ho*64 + wo
  int s = blockIdx.y;                        // channel split 0..SPLIT-1
  int b = m >> 12, pix = m & 4095;
  int ho = pix >> 6, wo = pix & 63;
  const float* xb = x + (size_t)b * CIN * 4096;

  float acc[27];
#pragma unroll
  for (int j = 0; j < 27; ++j) acc[j] = 0.f;

  int c0 = s * CPS;
  for (int ci = 0; ci < CPS; ++ci) {
    int c = c0 + ci;
    const float* xc = xb + (size_t)c * 4096;
    float d_off = 0.f, d_msk = 0.f;
#pragma unroll
    for (int t = 0; t < 9; ++t) {
      int gy = ho + t / 3 - 1, gx = wo + t % 3 - 1;
      bool ok = (gy >= 0) & (gy < HH) & (gx >= 0) & (gx < WW);
      float v = ok ? xc[gy * 64 + gx] : 0.f;
      d_off += v * off_dw[c * 9 + t];
      d_msk += v * mask_dw[c * 9 + t];
    }
#pragma unroll
    for (int j = 0; j < 18; ++j) acc[j] += d_off * off_pw[j * 256 + c];
#pragma unroll
    for (int j = 0; j < 9; ++j) acc[18 + j] += d_msk * mask_pw[j * 256 + c];
  }
  float* pp = part + ((size_t)s * NPIX + m) * 32;
#pragma unroll
  for (int j = 0; j < 27; ++j) pp[j] = acc[j];
}

// ---------------- Kernel 1b: reduce partials -> rec (sigmoid on mask) ----------------
__global__ __launch_bounds__(256) void offmask_reduce_kernel(
    const float* __restrict__ part, float* __restrict__ rec)
{
  int i = blockIdx.x * 256 + threadIdx.x;   // over NPIX*32
  int m = i >> 5, j = i & 31;
  if (j >= 27) { rec[i] = 0.f; return; }
  float sum = 0.f;
#pragma unroll
  for (int s = 0; s < SPLIT; ++s) sum += part[((size_t)s * NPIX + m) * 32 + j];
  rec[i] = (j < 18) ? sum : 2.f / (1.f + __expf(-sum));
}

// ---------------- Kernel 2: weight f32 (co,c,ki,kj) -> bf16 [co][kk*256 + c] ----------------
__global__ __launch_bounds__(256) void wconv_kernel(const float* __restrict__ w,
                                                    u16* __restrict__ wb)
{
  int i = blockIdx.x * 256 + threadIdx.x;     // over COUT*KD
  int co = i / KD, rem = i - co * KD;
  int c = rem / 9, kk = rem - c * 9;
  wb[co * KD + kk * 256 + c] = f2bf(w[i]);
}

// ---------------- Kernel 2b: x NCHW f32 -> xt NHWC bf16 ----------------
__global__ __launch_bounds__(256) void xpose_kernel(const float* __restrict__ x,
                                                    u16* __restrict__ xt)
{
  __shared__ float t[64][65];
  int ptile = blockIdx.x;   // 64-pixel tile within image (0..63)
  int ctile = blockIdx.y;   // 64-channel tile (0..3)
  int b     = blockIdx.z;
  int tid = threadIdx.x;
  const float* xb = x + (size_t)b * CIN * 4096 + (size_t)ctile * 64 * 4096 + ptile * 64;
#pragma unroll
  for (int i = 0; i < 16; ++i) {
    int c = i * 4 + (tid >> 6), p = tid & 63;
    t[c][p] = xb[(size_t)c * 4096 + p];
  }
  __syncthreads();
  u16* xo = xt + ((size_t)b * 4096 + ptile * 64) * 256 + ctile * 64;
#pragma unroll
  for (int i = 0; i < 16; ++i) {
    int p = i * 4 + (tid >> 6), c = tid & 63;
    xo[(size_t)p * 256 + c] = f2bf(t[c][p]);
  }
}

// ---------------- Kernel 3: deformable im2col from NHWC bf16 ----------------
__global__ __launch_bounds__(256) void im2col_nhwc_kernel(
    const u16* __restrict__ xt, const float* __restrict__ rec,
    u16* __restrict__ col)
{
  int tid = threadIdx.x;
  int wv = tid >> 6, lane = tid & 63;
  int m0 = blockIdx.x * 16 + wv * 4;

  for (int pi = 0; pi < 4; ++pi) {
    int m = m0 + pi;
    int b = m >> 12, pix = m & 4095;
    int ho = pix >> 6, wo = pix & 63;
    const float* rp = rec + (size_t)m * 32;
    u16* cp = col + (size_t)m * KD;
    const u16* xb = xt + ((size_t)b * 4096) * 256;

#pragma unroll
    for (int kk = 0; kk < 9; ++kk) {
      float dy = rp[kk * 2], dx = rp[kk * 2 + 1], msk = rp[18 + kk];
      float py = (float)(ho - 1 + (kk / 3)) + dy;
      float px = (float)(wo - 1 + (kk % 3)) + dx;
      float fy = floorf(py), fx = floorf(px);
      int y0 = (int)fy, x0 = (int)fx;
      float wy1 = py - fy, wy0 = 1.f - wy1;
      float wx1 = px - fx, wx0 = 1.f - wx1;
      float acc0 = 0.f, acc1 = 0.f, acc2 = 0.f, acc3 = 0.f;
#pragma unroll
      for (int cr = 0; cr < 4; ++cr) {
        int iy = y0 + (cr >> 1), ix = x0 + (cr & 1);
        bool valid = (iy >= 0) & (iy < HH) & (ix >= 0) & (ix < WW);
        int iyc = min(max(iy, 0), HH - 1), ixc = min(max(ix, 0), WW - 1);
        float wy = (cr >> 1) ? wy1 : wy0;
        float wx = (cr & 1) ? wx1 : wx0;
        float wt = valid ? (wy * wx * msk) : 0.f;
        ushort4v v = *(const ushort4v*)(xb + ((size_t)(iyc * 64 + ixc)) * 256 + lane * 4);
        acc0 += wt * bf2f(v[0]);
        acc1 += wt * bf2f(v[1]);
        acc2 += wt * bf2f(v[2]);
        acc3 += wt * bf2f(v[3]);
      }
      ushort4v o;
      o[0] = f2bf(acc0); o[1] = f2bf(acc1); o[2] = f2bf(acc2); o[3] = f2bf(acc3);
      *(ushort4v*)(cp + kk * 256 + lane * 4) = o;
    }
  }
}

// ---------------- Kernel 3-fallback: NCHW im2col ----------------
__global__ __launch_bounds__(256) void im2col_kernel(
    const float* __restrict__ x, const float* __restrict__ rec,
    u16* __restrict__ col)
{
  int row  = blockIdx.x;           // b*64 + ho
  int cq   = blockIdx.y;           // channel quarter 0..3
  int tid  = threadIdx.x;
  int lane = tid & 63;             // wo
  int w    = tid >> 6;             // 0..3
  int c0   = cq * 64 + w * 16;     // 16 channels per thread
  int b = row >> 6, ho = row & 63;
  int wo = lane;
  int m = row * 64 + wo;
  const float* xb = x + (size_t)b * CIN * 4096;
  const float* rp = rec + (size_t)m * 32;
  u16* cp = col + (size_t)m * KD;

  for (int kk = 0; kk < 9; ++kk) {
    int ki = kk / 3, kj = kk - ki * 3;
    float dy = rp[kk * 2], dx = rp[kk * 2 + 1], msk = rp[18 + kk];
    float py = (float)(ho - 1 + ki) + dy;
    float px = (float)(wo - 1 + kj) + dx;
    float fy = floorf(py), fx = floorf(px);
    int y0 = (int)fy, x0 = (int)fx;
    float wy1 = py - fy, wy0 = 1.f - wy1;
    float wx1 = px - fx, wx0 = 1.f - wx1;
    int idx[4]; float wt[4];
#pragma unroll
    for (int cr = 0; cr < 4; ++cr) {
      int iy = y0 + (cr >> 1), ix = x0 + (cr & 1);
      bool valid = (iy >= 0) & (iy < HH) & (ix >= 0) & (ix < WW);
      int iyc = min(max(iy, 0), HH - 1), ixc = min(max(ix, 0), WW - 1);
      idx[cr] = iyc * 64 + ixc;
      float wy = (cr >> 1) ? wy1 : wy0;
      float wx = (cr & 1) ? wx1 : wx0;
      wt[cr] = valid ? (wy * wx * msk) : 0.f;
    }
    short8v s0, s1;
#pragma unroll
    for (int i = 0; i < 8; ++i) {
      const float* xc = xb + (size_t)(c0 + i) * 4096;
      float s = wt[0] * xc[idx[0]] + wt[1] * xc[idx[1]] +
                wt[2] * xc[idx[2]] + wt[3] * xc[idx[3]];
      s0[i] = (short)f2bf(s);
    }
#pragma unroll
    for (int i = 0; i < 8; ++i) {
      const float* xc = xb + (size_t)(c0 + 8 + i) * 4096;
      float s = wt[0] * xc[idx[0]] + wt[1] * xc[idx[1]] +
                wt[2] * xc[idx[2]] + wt[3] * xc[idx[3]];
      s1[i] = (short)f2bf(s);
    }
    *(short8v*)(cp + kk * 256 + c0)     = s0;
    *(short8v*)(cp + kk * 256 + c0 + 8) = s1;
  }
}

// ---------------- Kernel 4: GEMM  C[co][m] = sum_k wb[co][k] * col[m][k]  (+bias) ----------------
// Tile 64(M) x 128(N), grid 512 (2 blocks/CU), 4 waves in 2x2, wave = 32x64.
// 2-phase double-buffer: STAGE(t+1) issued before compute(t); one barrier/iter.
// LDS swizzle: slot' = slot ^ (r&3) ^ ((r>>2)&3)  (involution; applied to gload
// SOURCE address with linear dest, and to ds_read slot). Bank class
// (r&1, slot) -> 2-way max = free.
__global__ __launch_bounds__(256) void gemm_kernel(
    const u16* __restrict__ A,    // wb  [COUT][KD]
    const u16* __restrict__ Bc,   // col [NPIX][KD]
    const float* __restrict__ bias,
    float* __restrict__ out)
{
  __shared__ __align__(16) u16 lA[2][64 * 32];
  __shared__ __align__(16) u16 lB[2][128 * 32];
  int tid = threadIdx.x;
  int bid = blockIdx.x;             // 0..511
  int mt = bid & 3, nt = bid >> 2;
  int i0 = mt * 64;                 // cout tile base
  int n0 = nt * 128;                // pixel tile base
  int wave = tid >> 6, lane = tid & 63;
  int wrM = wave >> 1, wcN = wave & 1;
  int rl = lane & 15, kq = lane >> 4;
  int sA = ((kq ^ (rl & 3) ^ ((rl >> 2) & 3))) * 8;   // read slot (u16 units)

  // staging: thread writes 16B at linear LDS offset tid*16 (A, B-chunk0) and
  // (tid+256)*16 (B-chunk1). Source slot swizzled; swz(r) has period 16 in r.
  int rA  = tid >> 2;
  int koA = ((tid & 3) ^ (rA & 3) ^ ((rA >> 2) & 3)) * 8;

  float4v acc[2][4];
#pragma unroll
  for (int m = 0; m < 2; ++m)
#pragma unroll
    for (int n = 0; n < 4; ++n) acc[m][n] = float4v{0.f, 0.f, 0.f, 0.f};

#define STAGE(t, bufi) do {                                                        \
    int k0_ = (t) * 32;                                                            \
    gload_lds16(A  + (size_t)(i0 + rA) * KD + k0_ + koA, lA[bufi] + tid * 8);      \
    gload_lds16(Bc + (size_t)(n0 + rA) * KD + k0_ + koA, lB[bufi] + tid * 8);      \
    gload_lds16(Bc + (size_t)(n0 + rA + 64) * KD + k0_ + koA,                      \
                lB[bufi] + (tid + 256) * 8);                                       \
  } while (0)

  STAGE(0, 0);
  __syncthreads();

  int cur = 0;
  for (int t = 0; t < 72; ++t) {
    if (t + 1 < 72) STAGE(t + 1, cur ^ 1);
    short8v af[2], bf[4];
#pragma unroll
    for (int m = 0; m < 2; ++m)
      af[m] = *(const short8v*)&lA[cur][(wrM * 32 + m * 16 + rl) * 32 + sA];
#pragma unroll
    for (int n = 0; n < 4; ++n)
      bf[n] = *(const short8v*)&lB[cur][(wcN * 64 + n * 16 + rl) * 32 + sA];
#pragma unroll
    for (int m = 0; m < 2; ++m)
#pragma unroll
      for (int n = 0; n < 4; ++n)
        acc[m][n] = __builtin_amdgcn_mfma_f32_16x16x32_bf16(af[m], bf[n], acc[m][n], 0, 0, 0);
    __syncthreads();   // drains vmcnt (stage t+1 landed) + lgkm; one barrier/iter
    cur ^= 1;
  }
#undef STAGE

  int b_img = n0 >> 12;
  int p_base = (n0 & 4095) + wcN * 64;
  float* ob = out + (size_t)b_img * COUT * 4096;
#pragma unroll
  for (int m = 0; m < 2; ++m) {
#pragma unroll
    for (int j = 0; j < 4; ++j) {
      int co = i0 + wrM * 32 + m * 16 + kq * 4 + j;
      float bv = bias[co];
#pragma unroll
      for (int n = 0; n < 4; ++n) {
        int pp = p_base + n * 16 + rl;
        ob[(size_t)co * 4096 + pp] = acc[m][n][j] + bv;
      }
    }
  }
}

extern "C" void kernel_launch(void* const* d_in, const int* in_sizes, int n_in,
                              void* d_out, int out_size, void* d_ws, size_t ws_size,
                              hipStream_t stream) {
  const float* x       = (const float*)d_in[0];
  const float* weight  = (const float*)d_in[1];
  const float* bias    = (const float*)d_in[2];
  const float* off_dw  = (const float*)d_in[3];
  const float* off_pw  = (const float*)d_in[4];
  const float* mask_dw = (const float*)d_in[5];
  const float* mask_pw = (const float*)d_in[6];

  // ws layout (NHWC path): rec 2MB | wb 1.18MB | xt 8.39MB | col 75.5MB = 87.2MB
  // part (33.5MB) aliases col (consumed by reduce before im2col writes col).
  float* rec  = (float*)d_ws;
  u16*   wb   = (u16*)((char*)d_ws + 2097152);
  float* out  = (float*)d_out;

  bool nhwc = ws_size >= 87162880ull;
  if (!nhwc && ws_size < 78774272ull) return;

  u16* xt  = (u16*)((char*)d_ws + 3276800);
  u16* col = nhwc ? (u16*)((char*)d_ws + 11665408) : (u16*)((char*)d_ws + 3276800);
  float* part = (float*)col;

  wconv_kernel<<<dim3(2304), dim3(256), 0, stream>>>(weight, wb);
  offmask_part_kernel<<<dim3(NPIX / 256, SPLIT), dim3(256), 0, stream>>>(
      x, off_dw, off_pw, mask_dw, mask_pw, part);
  offmask_reduce_kernel<<<dim3(NPIX * 32 / 256), dim3(256), 0, stream>>>(part, rec);
  if (nhwc) {
    xpose_kernel<<<dim3(64, 4, 4), dim3(256), 0, stream>>>(x, xt);
    im2col_nhwc_kernel<<<dim3(NPIX / 16), dim3(256), 0, stream>>>(xt, rec, col);
  } else {
    im2col_kernel<<<dim3(256, 4), dim3(256), 0, stream>>>(x, rec, col);
  }
  gemm_kernel<<<dim3(512), dim3(256), 0, stream>>>(wb, col, bias, out);
}

// Round 5
// 113.117 us; speedup vs baseline: 1.1423x; 1.1423x over previous
//
#include <hip/hip_runtime.h>

#define CIN   256
#define COUT  256
#define HH    64
#define WW    64
#define KD    2304         // CIN * 9
#define NPIX  16384        // B * HO * WO
#define SPLIT 16
#define CPS   (CIN / SPLIT)

typedef __attribute__((ext_vector_type(8))) short  short8v;
typedef __attribute__((ext_vector_type(4))) float  float4v;
typedef __attribute__((ext_vector_type(4))) unsigned short ushort4v;
typedef __attribute__((ext_vector_type(2))) unsigned int uint2v;
typedef unsigned int u32;
typedef unsigned short u16;

__device__ __forceinline__ u16 f2bf(float f) {
  union { float f; unsigned u; } v; v.f = f;
  unsigned r = v.u + 0x7FFFu + ((v.u >> 16) & 1u);
  return (u16)(r >> 16);
}
__device__ __forceinline__ float bf2f(u16 h) {
  union { unsigned u; float f; } v; v.u = ((unsigned)h) << 16;
  return v.f;
}

__device__ __forceinline__ void gload_lds16(const void* g, void* l) {
  __builtin_amdgcn_global_load_lds((const __attribute__((address_space(1))) u32*)g,
                                   (__attribute__((address_space(3))) u32*)l, 16, 0, 0);
}

// ---------------- Kernel 1a: offset/mask partials, channel-split ----------------
__global__ __launch_bounds__(256) void offmask_part_kernel(
    const float* __restrict__ x,
    const float* __restrict__ off_dw, const float* __restrict__ off_pw,
    const float* __restrict__ mask_dw, const float* __restrict__ mask_pw,
    float* __restrict__ part)
{
  int m = blockIdx.x * 256 + threadIdx.x;   // pixel id: b*4096 + ho*64 + wo
  int s = blockIdx.y;                        // channel split 0..SPLIT-1
  int b = m >> 12, pix = m & 4095;
  int ho = pix >> 6, wo = pix & 63;
  const float* xb = x + (size_t)b * CIN * 4096;

  float acc[27];
#pragma unroll
  for (int j = 0; j < 27; ++j) acc[j] = 0.f;

  int c0 = s * CPS;
  for (int ci = 0; ci < CPS; ++ci) {
    int c = c0 + ci;
    const float* xc = xb + (size_t)c * 4096;
    float d_off = 0.f, d_msk = 0.f;
#pragma unroll
    for (int t = 0; t < 9; ++t) {
      int gy = ho + t / 3 - 1, gx = wo + t % 3 - 1;
      bool ok = (gy >= 0) & (gy < HH) & (gx >= 0) & (gx < WW);
      float v = ok ? xc[gy * 64 + gx] : 0.f;
      d_off += v * off_dw[c * 9 + t];
      d_msk += v * mask_dw[c * 9 + t];
    }
#pragma unroll
    for (int j = 0; j < 18; ++j) acc[j] += d_off * off_pw[j * 256 + c];
#pragma unroll
    for (int j = 0; j < 9; ++j) acc[18 + j] += d_msk * mask_pw[j * 256 + c];
  }
  float* pp = part + ((size_t)s * NPIX + m) * 32;
#pragma unroll
  for (int j = 0; j < 27; ++j) pp[j] = acc[j];
}

// ---------------- Kernel 1b: reduce partials -> rec (sigmoid on mask) ----------------
__global__ __launch_bounds__(256) void offmask_reduce_kernel(
    const float* __restrict__ part, float* __restrict__ rec)
{
  int i = blockIdx.x * 256 + threadIdx.x;   // over NPIX*32
  int m = i >> 5, j = i & 31;
  if (j >= 27) { rec[i] = 0.f; return; }
  float sum = 0.f;
#pragma unroll
  for (int s = 0; s < SPLIT; ++s) sum += part[((size_t)s * NPIX + m) * 32 + j];
  rec[i] = (j < 18) ? sum : 2.f / (1.f + __expf(-sum));
}

// ---------------- Kernel 2: weight f32 (co,c,ki,kj) -> bf16 [co][kk*256 + c] ----------------
__global__ __launch_bounds__(256) void wconv_kernel(const float* __restrict__ w,
                                                    u16* __restrict__ wb)
{
  int i = blockIdx.x * 256 + threadIdx.x;     // over COUT*KD
  int co = i / KD, rem = i - co * KD;
  int c = rem / 9, kk = rem - c * 9;
  wb[co * KD + kk * 256 + c] = f2bf(w[i]);
}

// ---------------- Kernel 2b: x NCHW f32 -> xt NHWC bf16 ----------------
__global__ __launch_bounds__(256) void xpose_kernel(const float* __restrict__ x,
                                                    u16* __restrict__ xt)
{
  __shared__ float t[64][65];
  int ptile = blockIdx.x;   // 64-pixel tile within image (0..63)
  int ctile = blockIdx.y;   // 64-channel tile (0..3)
  int b     = blockIdx.z;
  int tid = threadIdx.x;
  const float* xb = x + (size_t)b * CIN * 4096 + (size_t)ctile * 64 * 4096 + ptile * 64;
#pragma unroll
  for (int i = 0; i < 16; ++i) {
    int c = i * 4 + (tid >> 6), p = tid & 63;
    t[c][p] = xb[(size_t)c * 4096 + p];
  }
  __syncthreads();
  u16* xo = xt + ((size_t)b * 4096 + ptile * 64) * 256 + ctile * 64;
#pragma unroll
  for (int i = 0; i < 16; ++i) {
    int p = i * 4 + (tid >> 6), c = tid & 63;
    xo[(size_t)p * 256 + c] = f2bf(t[c][p]);
  }
}

// ---------------- Kernel 4: FUSED deformable-im2col + GEMM ----------------
// Per block: C[256 cout][64 px]. Grid 256 blocks (one 64-px tile each), 512 thr
// (8 waves, 4Mx2N, wave = 64cout x 32px, acc[4][2]). K = 2304 = 9 taps x 256 ch,
// 72 steps of 32. B-tile (64px x 32ch) sampled from NHWC xt directly into LDS —
// col matrix never exists. 2-phase dbuf; corner loads for t+1 issued before
// MFMA(t) (T14 async-split; compiler inserts the vmcnt before the blend).
// Swizzle (rule #21, both sides): slot' = slot ^ (r&3) ^ ((r>>2)&3) applied to
// A gload SOURCE (linear dest), B ds_write slot, and all frag ds_reads.
__global__ __launch_bounds__(512) void gemm_fused_kernel(
    const u16* __restrict__ A,     // wb  [COUT][KD]
    const u16* __restrict__ xt,    // NHWC bf16 [B*4096][256]
    const float* __restrict__ rec, // [NPIX][32]
    const float* __restrict__ bias,
    float* __restrict__ out)
{
  __shared__ __align__(16) u16 lA[2][256 * 32];   // 2 x 16 KB
  __shared__ __align__(16) u16 lB[2][64 * 32];    // 2 x 4 KB
  const int tid = threadIdx.x;
  const int bid = blockIdx.x;            // 0..255
  const int m0  = bid * 64;              // pixel tile base (within one image)
  const int b_img = bid >> 6;
  const int wave = tid >> 6, lane = tid & 63;
  const int wm = wave >> 1, wn = wave & 1;
  const int rl = lane & 15, kq = lane >> 4;
  const int sA = (kq ^ (rl & 3) ^ ((rl >> 2) & 3)) * 8;   // frag read slot (u16)

  // A staging: thread covers rows (tid>>2) and (tid>>2)+128, 16B each
  const int rA  = tid >> 2;
  const int koA = ((tid & 3) ^ (rA & 3) ^ ((rA >> 2) & 3)) * 8;
  const u16* aRow0 = A + (size_t)rA * KD + koA;
  const u16* aRow1 = A + (size_t)(rA + 128) * KD + koA;

  // B sampling: thread -> (pixel spx, 4 channels sc4)
  const int spx = tid >> 3;              // 0..63
  const int sc4 = (tid & 7) * 4;         // 0,4,..,28
  const int m_px = m0 + spx;
  const int ho = (m_px & 4095) >> 6, wo = m_px & 63;
  const float* rp = rec + (size_t)m_px * 32;
  const u16* xb = xt + (size_t)b_img * 4096 * 256;
  // B LDS write addr (u16 units): row spx, phys slot = chslot ^ swz(spx)
  const int wAddr = spx * 32 +
                    ((((tid >> 1) & 3) ^ ((spx & 3) ^ ((spx >> 2) & 3))) * 8) +
                    (tid & 1) * 4;

  u32 cOff[4];   // corner row element-offsets into xb
  float cW[4];   // corner weights (incl. mask)

#define CALC_CORNERS(kk_) do {                                             \
    float dy = rp[(kk_) * 2], dx = rp[(kk_) * 2 + 1], msk = rp[18 + (kk_)];\
    float py  = (float)(ho - 1 + ((kk_) / 3)) + dy;                        \
    float pxf = (float)(wo - 1 + ((kk_) % 3)) + dx;                        \
    float fy = floorf(py), fx = floorf(pxf);                               \
    int y0 = (int)fy, x0 = (int)fx;                                        \
    float wy1 = py - fy, wy0 = 1.f - wy1;                                  \
    float wx1 = pxf - fx, wx0 = 1.f - wx1;                                 \
    _Pragma("unroll")                                                      \
    for (int cr = 0; cr < 4; ++cr) {                                       \
      int iy = y0 + (cr >> 1), ix = x0 + (cr & 1);                         \
      bool valid = (iy >= 0) & (iy < HH) & (ix >= 0) & (ix < WW);          \
      int iyc = min(max(iy, 0), HH - 1), ixc = min(max(ix, 0), WW - 1);    \
      cOff[cr] = (u32)(iyc * 64 + ixc) * 256;                              \
      float wy = (cr >> 1) ? wy1 : wy0;                                    \
      float wx = (cr & 1) ? wx1 : wx0;                                     \
      cW[cr] = valid ? (wy * wx * msk) : 0.f;                              \
    }                                                                      \
  } while (0)

#define STAGE_A(t, bufi) do {                                              \
    int k0_ = (t) * 32;                                                    \
    gload_lds16(aRow0 + k0_, lA[bufi] + tid * 8);                          \
    gload_lds16(aRow1 + k0_, lA[bufi] + (tid + 512) * 8);                  \
  } while (0)

  float4v acc[4][2];
#pragma unroll
  for (int m = 0; m < 4; ++m)
#pragma unroll
    for (int n = 0; n < 2; ++n) acc[m][n] = float4v{0.f, 0.f, 0.f, 0.f};

  // ---- prologue: sample K-step 0 into lB[0], stage A(0) ----
  {
    CALC_CORNERS(0);
    ushort4v v0 = *(const ushort4v*)(xb + cOff[0] + sc4);
    ushort4v v1 = *(const ushort4v*)(xb + cOff[1] + sc4);
    ushort4v v2 = *(const ushort4v*)(xb + cOff[2] + sc4);
    ushort4v v3 = *(const ushort4v*)(xb + cOff[3] + sc4);
    float a0 = cW[0]*bf2f(v0[0]) + cW[1]*bf2f(v1[0]) + cW[2]*bf2f(v2[0]) + cW[3]*bf2f(v3[0]);
    float a1 = cW[0]*bf2f(v0[1]) + cW[1]*bf2f(v1[1]) + cW[2]*bf2f(v2[1]) + cW[3]*bf2f(v3[1]);
    float a2 = cW[0]*bf2f(v0[2]) + cW[1]*bf2f(v1[2]) + cW[2]*bf2f(v2[2]) + cW[3]*bf2f(v3[2]);
    float a3 = cW[0]*bf2f(v0[3]) + cW[1]*bf2f(v1[3]) + cW[2]*bf2f(v2[3]) + cW[3]*bf2f(v3[3]);
    uint2v wv;
    wv[0] = (u32)f2bf(a0) | ((u32)f2bf(a1) << 16);
    wv[1] = (u32)f2bf(a2) | ((u32)f2bf(a3) << 16);
    *(uint2v*)&lB[0][wAddr] = wv;
    STAGE_A(0, 0);
  }
  __syncthreads();

#pragma unroll 2
  for (int ks = 0; ks < 72; ++ks) {
    const int cur = ks & 1;
    ushort4v v0, v1, v2, v3;
    const bool have = (ks < 71);
    if (have) {
      STAGE_A(ks + 1, cur ^ 1);
      int ksn = ks + 1;
      if ((ksn & 7) == 0) CALC_CORNERS(ksn >> 3);
      int c0n = (ksn & 7) * 32;
      v0 = *(const ushort4v*)(xb + cOff[0] + c0n + sc4);
      v1 = *(const ushort4v*)(xb + cOff[1] + c0n + sc4);
      v2 = *(const ushort4v*)(xb + cOff[2] + c0n + sc4);
      v3 = *(const ushort4v*)(xb + cOff[3] + c0n + sc4);
    }
    short8v af[4], bf[2];
#pragma unroll
    for (int m = 0; m < 4; ++m)
      af[m] = *(const short8v*)&lA[cur][(wm * 64 + m * 16 + rl) * 32 + sA];
#pragma unroll
    for (int n = 0; n < 2; ++n)
      bf[n] = *(const short8v*)&lB[cur][(wn * 32 + n * 16 + rl) * 32 + sA];
#pragma unroll
    for (int m = 0; m < 4; ++m)
#pragma unroll
      for (int n = 0; n < 2; ++n)
        acc[m][n] = __builtin_amdgcn_mfma_f32_16x16x32_bf16(af[m], bf[n], acc[m][n], 0, 0, 0);
    if (have) {
      float a0 = cW[0]*bf2f(v0[0]) + cW[1]*bf2f(v1[0]) + cW[2]*bf2f(v2[0]) + cW[3]*bf2f(v3[0]);
      float a1 = cW[0]*bf2f(v0[1]) + cW[1]*bf2f(v1[1]) + cW[2]*bf2f(v2[1]) + cW[3]*bf2f(v3[1]);
      float a2 = cW[0]*bf2f(v0[2]) + cW[1]*bf2f(v1[2]) + cW[2]*bf2f(v2[2]) + cW[3]*bf2f(v3[2]);
      float a3 = cW[0]*bf2f(v0[3]) + cW[1]*bf2f(v1[3]) + cW[2]*bf2f(v2[3]) + cW[3]*bf2f(v3[3]);
      uint2v wv;
      wv[0] = (u32)f2bf(a0) | ((u32)f2bf(a1) << 16);
      wv[1] = (u32)f2bf(a2) | ((u32)f2bf(a3) << 16);
      *(uint2v*)&lB[cur ^ 1][wAddr] = wv;
    }
    __syncthreads();
  }
#undef STAGE_A
#undef CALC_CORNERS

  const int p_base = (m0 & 4095) + wn * 32;
  float* ob = out + (size_t)b_img * COUT * 4096;
#pragma unroll
  for (int m = 0; m < 4; ++m) {
#pragma unroll
    for (int j = 0; j < 4; ++j) {
      int co = wm * 64 + m * 16 + kq * 4 + j;
      float bv = bias[co];
#pragma unroll
      for (int n = 0; n < 2; ++n) {
        int pp = p_base + n * 16 + rl;
        ob[(size_t)co * 4096 + pp] = acc[m][n][j] + bv;
      }
    }
  }
}

extern "C" void kernel_launch(void* const* d_in, const int* in_sizes, int n_in,
                              void* d_out, int out_size, void* d_ws, size_t ws_size,
                              hipStream_t stream) {
  const float* x       = (const float*)d_in[0];
  const float* weight  = (const float*)d_in[1];
  const float* bias    = (const float*)d_in[2];
  const float* off_dw  = (const float*)d_in[3];
  const float* off_pw  = (const float*)d_in[4];
  const float* mask_dw = (const float*)d_in[5];
  const float* mask_pw = (const float*)d_in[6];

  // ws layout: rec 2MB @0 | wb 1.18MB @2,097,152 | xt 8.39MB @3,276,800 |
  //            part 33.5MB @11,665,408  => total 45,219,840 B
  if (ws_size < 45219840ull) return;
  float* rec  = (float*)d_ws;
  u16*   wb   = (u16*)((char*)d_ws + 2097152);
  u16*   xt   = (u16*)((char*)d_ws + 3276800);
  float* part = (float*)((char*)d_ws + 11665408);
  float* out  = (float*)d_out;

  wconv_kernel<<<dim3(2304), dim3(256), 0, stream>>>(weight, wb);
  offmask_part_kernel<<<dim3(NPIX / 256, SPLIT), dim3(256), 0, stream>>>(
      x, off_dw, off_pw, mask_dw, mask_pw, part);
  offmask_reduce_kernel<<<dim3(NPIX * 32 / 256), dim3(256), 0, stream>>>(part, rec);
  xpose_kernel<<<dim3(64, 4, 4), dim3(256), 0, stream>>>(x, xt);
  gemm_fused_kernel<<<dim3(256), dim3(512), 0, stream>>>(wb, xt, rec, bias, out);
}

// Round 6
// 106.534 us; speedup vs baseline: 1.2129x; 1.0618x over previous
//
#include <hip/hip_runtime.h>

#define CIN   256
#define COUT  256
#define HH    64
#define WW    64
#define KD    2304         // CIN * 9
#define NPIX  16384        // B * HO * WO
#define SPLIT 16
#define CPS   (CIN / SPLIT)

typedef __attribute__((ext_vector_type(8))) short  short8v;
typedef __attribute__((ext_vector_type(4))) float  float4v;
typedef __attribute__((ext_vector_type(4))) unsigned short ushort4v;
typedef __attribute__((ext_vector_type(2))) unsigned int uint2v;
typedef unsigned int u32;
typedef unsigned short u16;

__device__ __forceinline__ u16 f2bf(float f) {
  union { float f; unsigned u; } v; v.f = f;
  unsigned r = v.u + 0x7FFFu + ((v.u >> 16) & 1u);
  return (u16)(r >> 16);
}
__device__ __forceinline__ float bf2f(u16 h) {
  union { unsigned u; float f; } v; v.u = ((unsigned)h) << 16;
  return v.f;
}

__device__ __forceinline__ void gload_lds16(const void* g, void* l) {
  __builtin_amdgcn_global_load_lds((const __attribute__((address_space(1))) u32*)g,
                                   (__attribute__((address_space(3))) u32*)l, 16, 0, 0);
}

// ---------------- Kernel 1a: offset/mask partials, channel-split ----------------
__global__ __launch_bounds__(256) void offmask_part_kernel(
    const float* __restrict__ x,
    const float* __restrict__ off_dw, const float* __restrict__ off_pw,
    const float* __restrict__ mask_dw, const float* __restrict__ mask_pw,
    float* __restrict__ part)
{
  int m = blockIdx.x * 256 + threadIdx.x;   // pixel id: b*4096 + ho*64 + wo
  int s = blockIdx.y;                        // channel split 0..SPLIT-1
  int b = m >> 12, pix = m & 4095;
  int ho = pix >> 6, wo = pix & 63;
  const float* xb = x + (size_t)b * CIN * 4096;

  float acc[27];
#pragma unroll
  for (int j = 0; j < 27; ++j) acc[j] = 0.f;

  int c0 = s * CPS;
  for (int ci = 0; ci < CPS; ++ci) {
    int c = c0 + ci;
    const float* xc = xb + (size_t)c * 4096;
    float d_off = 0.f, d_msk = 0.f;
#pragma unroll
    for (int t = 0; t < 9; ++t) {
      int gy = ho + t / 3 - 1, gx = wo + t % 3 - 1;
      bool ok = (gy >= 0) & (gy < HH) & (gx >= 0) & (gx < WW);
      float v = ok ? xc[gy * 64 + gx] : 0.f;
      d_off += v * off_dw[c * 9 + t];
      d_msk += v * mask_dw[c * 9 + t];
    }
#pragma unroll
    for (int j = 0; j < 18; ++j) acc[j] += d_off * off_pw[j * 256 + c];
#pragma unroll
    for (int j = 0; j < 9; ++j) acc[18 + j] += d_msk * mask_pw[j * 256 + c];
  }
  float* pp = part + ((size_t)s * NPIX + m) * 32;
#pragma unroll
  for (int j = 0; j < 27; ++j) pp[j] = acc[j];
}

// ---------------- Kernel 1b: reduce partials -> rec (sigmoid on mask) ----------------
__global__ __launch_bounds__(256) void offmask_reduce_kernel(
    const float* __restrict__ part, float* __restrict__ rec)
{
  int i = blockIdx.x * 256 + threadIdx.x;   // over NPIX*32
  int m = i >> 5, j = i & 31;
  if (j >= 27) { rec[i] = 0.f; return; }
  float sum = 0.f;
#pragma unroll
  for (int s = 0; s < SPLIT; ++s) sum += part[((size_t)s * NPIX + m) * 32 + j];
  rec[i] = (j < 18) ? sum : 2.f / (1.f + __expf(-sum));
}

// ---------------- Kernel 2: weight f32 (co,c,ki,kj) -> bf16 [co][kk*256 + c] ----------------
__global__ __launch_bounds__(256) void wconv_kernel(const float* __restrict__ w,
                                                    u16* __restrict__ wb)
{
  int i = blockIdx.x * 256 + threadIdx.x;     // over COUT*KD
  int co = i / KD, rem = i - co * KD;
  int c = rem / 9, kk = rem - c * 9;
  wb[co * KD + kk * 256 + c] = f2bf(w[i]);
}

// ---------------- Kernel 2b: x NCHW f32 -> xt NHWC bf16 ----------------
__global__ __launch_bounds__(256) void xpose_kernel(const float* __restrict__ x,
                                                    u16* __restrict__ xt)
{
  __shared__ float t[64][65];
  int ptile = blockIdx.x;   // 64-pixel tile within image (0..63)
  int ctile = blockIdx.y;   // 64-channel tile (0..3)
  int b     = blockIdx.z;
  int tid = threadIdx.x;
  const float* xb = x + (size_t)b * CIN * 4096 + (size_t)ctile * 64 * 4096 + ptile * 64;
#pragma unroll
  for (int i = 0; i < 16; ++i) {
    int c = i * 4 + (tid >> 6), p = tid & 63;
    t[c][p] = xb[(size_t)c * 4096 + p];
  }
  __syncthreads();
  u16* xo = xt + ((size_t)b * 4096 + ptile * 64) * 256 + ctile * 64;
#pragma unroll
  for (int i = 0; i < 16; ++i) {
    int p = i * 4 + (tid >> 6), c = tid & 63;
    xo[(size_t)p * 256 + c] = f2bf(t[c][p]);
  }
}

// ---------------- Kernel 4: FUSED deformable-im2col + GEMM, K-split x2 ----------------
// Grid 512: bid = (ptile<<1)|h. Half h covers channels h*128..h*128+127 for all
// 9 taps: K=1152, 36 steps of 32. 2 blocks/CU -> 4 waves/SIMD; one block's
// barrier drain hides under the other's compute. Half 0 -> out (+bias),
// half 1 -> tmp; add_kernel folds. Schedule/swizzle identical to R5 (proven).
__global__ __launch_bounds__(512) void gemm_fused_kernel(
    const u16* __restrict__ A,     // wb  [COUT][KD]
    const u16* __restrict__ xt,    // NHWC bf16 [B*4096][256]
    const float* __restrict__ rec, // [NPIX][32]
    const float* __restrict__ bias,
    float* __restrict__ out,       // half 0 dest (+bias)
    float* __restrict__ tmp)       // half 1 dest (raw)
{
  __shared__ __align__(16) u16 lA[2][256 * 32];   // 2 x 16 KB
  __shared__ __align__(16) u16 lB[2][64 * 32];    // 2 x 4 KB
  const int tid = threadIdx.x;
  const int bid = blockIdx.x;            // 0..511
  const int h   = bid & 1;               // K half
  const int ptile = bid >> 1;            // 0..255
  const int m0  = ptile * 64;            // pixel tile base
  const int b_img = ptile >> 6;
  const int cbase = h * 128;             // channel base of this half
  const int wave = tid >> 6, lane = tid & 63;
  const int wm = wave >> 1, wn = wave & 1;
  const int rl = lane & 15, kq = lane >> 4;
  const int sA = (kq ^ (rl & 3) ^ ((rl >> 2) & 3)) * 8;   // frag read slot (u16)

  // A staging: thread covers rows (tid>>2) and (tid>>2)+128, 16B each
  const int rA  = tid >> 2;
  const int koA = ((tid & 3) ^ (rA & 3) ^ ((rA >> 2) & 3)) * 8;
  const u16* aRow0 = A + (size_t)rA * KD + koA;
  const u16* aRow1 = A + (size_t)(rA + 128) * KD + koA;

  // B sampling: thread -> (pixel spx, 4 channels sc4 within current 32-chunk)
  const int spx = tid >> 3;              // 0..63
  const int sc4 = (tid & 7) * 4;         // 0,4,..,28
  const int m_px = m0 + spx;
  const int ho = (m_px & 4095) >> 6, wo = m_px & 63;
  const float* rp = rec + (size_t)m_px * 32;
  const u16* xb = xt + (size_t)b_img * 4096 * 256;
  const int wAddr = spx * 32 +
                    ((((tid >> 1) & 3) ^ ((spx & 3) ^ ((spx >> 2) & 3))) * 8) +
                    (tid & 1) * 4;

  u32 cOff[4];   // corner row element-offsets into xb
  float cW[4];   // corner weights (incl. mask)

  // step t (0..35): kk = t>>2, chunk col = kk*256 + cbase + (t&3)*32
#define KCOL(t_) (((t_) >> 2) * 256 + cbase + ((t_) & 3) * 32)

#define CALC_CORNERS(kk_) do {                                             \
    float dy = rp[(kk_) * 2], dx = rp[(kk_) * 2 + 1], msk = rp[18 + (kk_)];\
    float py  = (float)(ho - 1 + ((kk_) / 3)) + dy;                        \
    float pxf = (float)(wo - 1 + ((kk_) % 3)) + dx;                        \
    float fy = floorf(py), fx = floorf(pxf);                               \
    int y0 = (int)fy, x0 = (int)fx;                                        \
    float wy1 = py - fy, wy0 = 1.f - wy1;                                  \
    float wx1 = pxf - fx, wx0 = 1.f - wx1;                                 \
    _Pragma("unroll")                                                      \
    for (int cr = 0; cr < 4; ++cr) {                                       \
      int iy = y0 + (cr >> 1), ix = x0 + (cr & 1);                         \
      bool valid = (iy >= 0) & (iy < HH) & (ix >= 0) & (ix < WW);          \
      int iyc = min(max(iy, 0), HH - 1), ixc = min(max(ix, 0), WW - 1);    \
      cOff[cr] = (u32)(iyc * 64 + ixc) * 256;                              \
      float wy = (cr >> 1) ? wy1 : wy0;                                    \
      float wx = (cr & 1) ? wx1 : wx0;                                     \
      cW[cr] = valid ? (wy * wx * msk) : 0.f;                              \
    }                                                                      \
  } while (0)

#define STAGE_A(t, bufi) do {                                              \
    int k0_ = KCOL(t);                                                     \
    gload_lds16(aRow0 + k0_, lA[bufi] + tid * 8);                          \
    gload_lds16(aRow1 + k0_, lA[bufi] + (tid + 512) * 8);                  \
  } while (0)

  float4v acc[4][2];
#pragma unroll
  for (int m = 0; m < 4; ++m)
#pragma unroll
    for (int n = 0; n < 2; ++n) acc[m][n] = float4v{0.f, 0.f, 0.f, 0.f};

  // ---- prologue: sample K-step 0 into lB[0], stage A(0) ----
  {
    CALC_CORNERS(0);
    int c0n = cbase + sc4;
    ushort4v v0 = *(const ushort4v*)(xb + cOff[0] + c0n);
    ushort4v v1 = *(const ushort4v*)(xb + cOff[1] + c0n);
    ushort4v v2 = *(const ushort4v*)(xb + cOff[2] + c0n);
    ushort4v v3 = *(const ushort4v*)(xb + cOff[3] + c0n);
    float a0 = cW[0]*bf2f(v0[0]) + cW[1]*bf2f(v1[0]) + cW[2]*bf2f(v2[0]) + cW[3]*bf2f(v3[0]);
    float a1 = cW[0]*bf2f(v0[1]) + cW[1]*bf2f(v1[1]) + cW[2]*bf2f(v2[1]) + cW[3]*bf2f(v3[1]);
    float a2 = cW[0]*bf2f(v0[2]) + cW[1]*bf2f(v1[2]) + cW[2]*bf2f(v2[2]) + cW[3]*bf2f(v3[2]);
    float a3 = cW[0]*bf2f(v0[3]) + cW[1]*bf2f(v1[3]) + cW[2]*bf2f(v2[3]) + cW[3]*bf2f(v3[3]);
    uint2v wv;
    wv[0] = (u32)f2bf(a0) | ((u32)f2bf(a1) << 16);
    wv[1] = (u32)f2bf(a2) | ((u32)f2bf(a3) << 16);
    *(uint2v*)&lB[0][wAddr] = wv;
    STAGE_A(0, 0);
  }
  __syncthreads();

#pragma unroll 4
  for (int ks = 0; ks < 36; ++ks) {
    const int cur = ks & 1;
    ushort4v v0, v1, v2, v3;
    const bool have = (ks < 35);
    if (have) {
      STAGE_A(ks + 1, cur ^ 1);
      int ksn = ks + 1;
      if ((ksn & 3) == 0) CALC_CORNERS(ksn >> 2);
      int c0n = cbase + (ksn & 3) * 32 + sc4;
      v0 = *(const ushort4v*)(xb + cOff[0] + c0n);
      v1 = *(const ushort4v*)(xb + cOff[1] + c0n);
      v2 = *(const ushort4v*)(xb + cOff[2] + c0n);
      v3 = *(const ushort4v*)(xb + cOff[3] + c0n);
    }
    short8v af[4], bf[2];
#pragma unroll
    for (int m = 0; m < 4; ++m)
      af[m] = *(const short8v*)&lA[cur][(wm * 64 + m * 16 + rl) * 32 + sA];
#pragma unroll
    for (int n = 0; n < 2; ++n)
      bf[n] = *(const short8v*)&lB[cur][(wn * 32 + n * 16 + rl) * 32 + sA];
#pragma unroll
    for (int m = 0; m < 4; ++m)
#pragma unroll
      for (int n = 0; n < 2; ++n)
        acc[m][n] = __builtin_amdgcn_mfma_f32_16x16x32_bf16(af[m], bf[n], acc[m][n], 0, 0, 0);
    if (have) {
      float a0 = cW[0]*bf2f(v0[0]) + cW[1]*bf2f(v1[0]) + cW[2]*bf2f(v2[0]) + cW[3]*bf2f(v3[0]);
      float a1 = cW[0]*bf2f(v0[1]) + cW[1]*bf2f(v1[1]) + cW[2]*bf2f(v2[1]) + cW[3]*bf2f(v3[1]);
      float a2 = cW[0]*bf2f(v0[2]) + cW[1]*bf2f(v1[2]) + cW[2]*bf2f(v2[2]) + cW[3]*bf2f(v3[2]);
      float a3 = cW[0]*bf2f(v0[3]) + cW[1]*bf2f(v1[3]) + cW[2]*bf2f(v2[3]) + cW[3]*bf2f(v3[3]);
      uint2v wv;
      wv[0] = (u32)f2bf(a0) | ((u32)f2bf(a1) << 16);
      wv[1] = (u32)f2bf(a2) | ((u32)f2bf(a3) << 16);
      *(uint2v*)&lB[cur ^ 1][wAddr] = wv;
    }
    __syncthreads();
  }
#undef STAGE_A
#undef CALC_CORNERS
#undef KCOL

  const int p_base = (m0 & 4095) + wn * 32;
  float* db = (h ? tmp : out) + (size_t)b_img * COUT * 4096;
#pragma unroll
  for (int m = 0; m < 4; ++m) {
#pragma unroll
    for (int j = 0; j < 4; ++j) {
      int co = wm * 64 + m * 16 + kq * 4 + j;
      float bv = h ? 0.f : bias[co];
#pragma unroll
      for (int n = 0; n < 2; ++n) {
        int pp = p_base + n * 16 + rl;
        db[(size_t)co * 4096 + pp] = acc[m][n][j] + bv;
      }
    }
  }
}

// ---------------- Kernel 5: out += tmp ----------------
__global__ __launch_bounds__(256) void add_kernel(float* __restrict__ out,
                                                  const float* __restrict__ tmp)
{
  int i = blockIdx.x * 256 + threadIdx.x;    // over (COUT*NPIX)/4 float4s
  float4v a = *(const float4v*)(out + (size_t)i * 4);
  float4v b = *(const float4v*)(tmp + (size_t)i * 4);
  a += b;
  *(float4v*)(out + (size_t)i * 4) = a;
}

extern "C" void kernel_launch(void* const* d_in, const int* in_sizes, int n_in,
                              void* d_out, int out_size, void* d_ws, size_t ws_size,
                              hipStream_t stream) {
  const float* x       = (const float*)d_in[0];
  const float* weight  = (const float*)d_in[1];
  const float* bias    = (const float*)d_in[2];
  const float* off_dw  = (const float*)d_in[3];
  const float* off_pw  = (const float*)d_in[4];
  const float* mask_dw = (const float*)d_in[5];
  const float* mask_pw = (const float*)d_in[6];

  // ws layout: rec 2MB @0 | wb 1.18MB @2,097,152 | xt 8.39MB @3,276,800 |
  //            part 33.5MB @11,665,408 (aliased by tmp 16.7MB after reduce)
  //            => total 45,219,840 B
  if (ws_size < 45219840ull) return;
  float* rec  = (float*)d_ws;
  u16*   wb   = (u16*)((char*)d_ws + 2097152);
  u16*   xt   = (u16*)((char*)d_ws + 3276800);
  float* part = (float*)((char*)d_ws + 11665408);
  float* tmp  = part;                       // alias: part consumed before gemm
  float* out  = (float*)d_out;

  wconv_kernel<<<dim3(2304), dim3(256), 0, stream>>>(weight, wb);
  offmask_part_kernel<<<dim3(NPIX / 256, SPLIT), dim3(256), 0, stream>>>(
      x, off_dw, off_pw, mask_dw, mask_pw, part);
  offmask_reduce_kernel<<<dim3(NPIX * 32 / 256), dim3(256), 0, stream>>>(part, rec);
  xpose_kernel<<<dim3(64, 4, 4), dim3(256), 0, stream>>>(x, xt);
  gemm_fused_kernel<<<dim3(512), dim3(512), 0, stream>>>(wb, xt, rec, bias, out, tmp);
  add_kernel<<<dim3((COUT * NPIX / 4) / 256), dim3(256), 0, stream>>>(out, tmp);
}